// Round 1
// 202.459 us; speedup vs baseline: 1.0380x; 1.0380x over previous
//
#include <hip/hip_runtime.h>
#include <hip/hip_fp16.h>
#include <math.h>

// ---------------------------------------------------------------------------
// GCN encoder. Aggregation = gather over a single-pass device-built ELL table:
//   k_scatter: r = atomicAdd(&cnt[c],1); ell[c*48+r] = src_row_byte_offset
// (rank from the atomic return value = no degree pass, no row_start, no pads).
// v2: XCD-sliced scatter — nodes split into 8 contiguous slices; slice =
// blockIdx&7 so each XCD's blocks write only a 1.2MB L2-resident ell slice
// (kills the ~5x cross-XCD partial-line write amplification seen in rocprof).
// Edge list is re-scanned once per slice; L3 (256MB) absorbs the re-reads.
// Rows are pre-scaled fp16: hs[r] = dinv[r]*(x@W1)[r], h2s[r] = dinv[r]*h2[r];
// self loop is handled by initializing the accumulator from the node's own row.
// Gather entries beyond exact degree are clamped (cndmask) to a zero row.
// ---------------------------------------------------------------------------

#define ELLW 48

typedef _Float16 half8 __attribute__((ext_vector_type(8)));
typedef float f32x4 __attribute__((ext_vector_type(4)));

__global__ void k_init(int* __restrict__ cnt, int n) {
    int i = blockIdx.x * blockDim.x + threadIdx.x;
    if (i < n) cnt[i] = 0;
}

// XCD-sliced single-pass ELL build: rank comes from the atomic itself.
// slice = blockIdx&7 -> round-robin XCD mapping; each slice's cnt+ell working
// set (~25KB + ~1.2MB) stays resident in that XCD's L2 so writebacks merge.
__global__ __launch_bounds__(256) void k_scatter(
    const int* __restrict__ row, const int* __restrict__ col,
    int* __restrict__ cnt, int* __restrict__ ell, int E, int slice_sz) {
    int slice = blockIdx.x & 7;
    int lo = slice * slice_sz;
    int hi = lo + slice_sz;
    int nchunk = gridDim.x >> 3;
    int stride = nchunk * 256;
    int v0 = (blockIdx.x >> 3) * 256 + threadIdx.x;
    int nv = E >> 2;
    const int4* c4p = (const int4*)col;
    const int4* r4p = (const int4*)row;
    for (int v = v0; v < nv; v += stride) {
        int4 c4 = c4p[v];
        int4 r4 = r4p[v];
        if (c4.x >= lo && c4.x < hi) {
            int rk = atomicAdd(&cnt[c4.x], 1);
            if (rk < ELLW) ell[c4.x * ELLW + rk] = r4.x << 7;
        }
        if (c4.y >= lo && c4.y < hi) {
            int rk = atomicAdd(&cnt[c4.y], 1);
            if (rk < ELLW) ell[c4.y * ELLW + rk] = r4.y << 7;
        }
        if (c4.z >= lo && c4.z < hi) {
            int rk = atomicAdd(&cnt[c4.z], 1);
            if (rk < ELLW) ell[c4.z * ELLW + rk] = r4.z << 7;
        }
        if (c4.w >= lo && c4.w < hi) {
            int rk = atomicAdd(&cnt[c4.w], 1);
            if (rk < ELLW) ell[c4.w * ELLW + rk] = r4.w << 7;
        }
    }
    if ((blockIdx.x >> 3) == 0) {        // tail edges (E % 4)
        for (int e = (nv << 2) + threadIdx.x; e < E; e += 256) {
            int c = col[e];
            if (c >= lo && c < hi) {
                int rk = atomicAdd(&cnt[c], 1);
                if (rk < ELLW) ell[c * ELLW + rk] = row[e] << 7;
            }
        }
    }
}

__global__ void k_dinv(const int* __restrict__ cnt, float* __restrict__ dinv, int n) {
    int i = blockIdx.x * blockDim.x + threadIdx.x;
    if (i < n) dinv[i] = rsqrtf((float)(cnt[i] + 1));    // +1 = self loop
}

// Pack W1 into f16 B-frag layout (4 col-tiles x 4 k-steps) and [W2|W3] into
// 5 tiles x 2 k-steps. B-frag: lane L holds B[k=(L>>4)*8+j][col=tile*16+(L&15)].
__global__ void k_pack(const float* __restrict__ W1, const float* __restrict__ W2,
                       const float* __restrict__ W3, _Float16* __restrict__ W1g,
                       _Float16* __restrict__ Bg) {
    int idx = blockIdx.x * 256 + threadIdx.x;
    if (idx < 8192) {
        int j = idx & 7, L = (idx >> 3) & 63, s = (idx >> 9) & 3, t = idx >> 11;
        int k = s * 32 + (L >> 4) * 8 + j;
        int c = t * 16 + (L & 15);
        W1g[idx] = (_Float16)W1[k * 64 + c];
    } else if (idx < 8192 + 5120) {
        int i2 = idx - 8192;
        int j = i2 & 7, L = (i2 >> 3) & 63, s = (i2 >> 9) & 1, u = i2 >> 10;
        int k = s * 32 + (L >> 4) * 8 + j;
        int c = (L & 15);
        float v;
        if (u < 4) v = W2[k * 64 + u * 16 + c];
        else v = (c < 6) ? W3[k * 6 + c] : 0.f;
        Bg[i2] = (_Float16)v;
    }
}

// hs = (x @ W1) * dinv, via f16 MFMA. Block = 4 waves x 16 nodes = 64 nodes.
__global__ __launch_bounds__(256, 4) void k_gemm1(
    const float* __restrict__ x, const _Float16* __restrict__ W1g,
    const float* __restrict__ dinv, uint* __restrict__ hs,
    uint* __restrict__ h2s, int n) {
    int tid = threadIdx.x;
    if (blockIdx.x == 0) {               // zero rows for clamped gathers
        if (tid < 32) hs[(size_t)n * 32 + tid] = 0u;
        else if (tid < 64) h2s[(size_t)n * 32 + (tid - 32)] = 0u;
    }
    int lane = tid & 63, wid = tid >> 6;
    int m16 = lane & 15, quad = lane >> 4;
    int node0 = blockIdx.x * 64 + wid * 16;
    int arow = node0 + m16;
    if (arow >= n) arow = n - 1;
    const float* xr = x + (size_t)arow * 128;
    half8 A[4];
#pragma unroll
    for (int s = 0; s < 4; s++) {
        const float4* p = (const float4*)(xr + s * 32 + quad * 8);
        float4 f0 = p[0], f1 = p[1];
        half8 a;
        a[0] = (_Float16)f0.x; a[1] = (_Float16)f0.y;
        a[2] = (_Float16)f0.z; a[3] = (_Float16)f0.w;
        a[4] = (_Float16)f1.x; a[5] = (_Float16)f1.y;
        a[6] = (_Float16)f1.z; a[7] = (_Float16)f1.w;
        A[s] = a;
    }
    float dsc[4];
#pragma unroll
    for (int r = 0; r < 4; r++) {
        int nd = node0 + quad * 4 + r;
        dsc[r] = dinv[nd < n ? nd : n - 1];
    }
    const half8* Wv = (const half8*)W1g;
#pragma unroll
    for (int t = 0; t < 4; t++) {
        f32x4 acc = {0.f, 0.f, 0.f, 0.f};
#pragma unroll
        for (int s = 0; s < 4; s++)
            acc = __builtin_amdgcn_mfma_f32_16x16x32_f16(A[s], Wv[(t * 4 + s) * 64 + lane], acc, 0, 0, 0);
#pragma unroll
        for (int r = 0; r < 4; r++) {
            int nd = node0 + quad * 4 + r;
            float v = acc[r] * dsc[r];
            float vo = __shfl_xor(v, 1, 64);
            if (!(m16 & 1) && nd < n) {
                __half2 pk = __floats2half2_rn(v, vo);
                hs[(size_t)nd * 32 + t * 8 + (m16 >> 1)] = *(uint*)&pk;
            }
        }
    }
}

// Branchless pipelined 4-node gather (accumulators pre-seeded with self rows).
#define GATHER_BODY(SRC)                                                      \
    int4 o1[4], o2[4];                                                        \
    uint4 u0[4], u1[4];                                                       \
    {                                                                         \
        int4 o0[4];                                                           \
        _Pragma("unroll") for (int p = 0; p < 4; p++) o0[p] = ldidx(p, 0);    \
        _Pragma("unroll") for (int p = 0; p < 4; p++) o1[p] = ldidx(p, 8);    \
        _Pragma("unroll") for (int p = 0; p < 4; p++) {                       \
            u0[p].x = *(const uint*)(SRC + o0[p].x + m4);                     \
            u0[p].y = *(const uint*)(SRC + o0[p].y + m4);                     \
            u0[p].z = *(const uint*)(SRC + o0[p].z + m4);                     \
            u0[p].w = *(const uint*)(SRC + o0[p].w + m4);                     \
        }                                                                     \
    }                                                                         \
    for (int jb = 0; jb < Pmax; jb += 8) {                                    \
        _Pragma("unroll") for (int p = 0; p < 4; p++) o2[p] = ldidx(p, jb + 16); \
        _Pragma("unroll") for (int p = 0; p < 4; p++) {                       \
            u1[p].x = *(const uint*)(SRC + o1[p].x + m4);                     \
            u1[p].y = *(const uint*)(SRC + o1[p].y + m4);                     \
            u1[p].z = *(const uint*)(SRC + o1[p].z + m4);                     \
            u1[p].w = *(const uint*)(SRC + o1[p].w + m4);                     \
        }                                                                     \
        _Pragma("unroll") for (int p = 0; p < 4; p++) {                       \
            float2 f;                                                         \
            f = __half22float2(*(__half2*)&u0[p].x); ax[p] += f.x; ay[p] += f.y; \
            f = __half22float2(*(__half2*)&u0[p].y); ax[p] += f.x; ay[p] += f.y; \
            f = __half22float2(*(__half2*)&u0[p].z); ax[p] += f.x; ay[p] += f.y; \
            f = __half22float2(*(__half2*)&u0[p].w); ax[p] += f.x; ay[p] += f.y; \
        }                                                                     \
        _Pragma("unroll") for (int p = 0; p < 4; p++) { o1[p] = o2[p]; u0[p] = u1[p]; } \
    }

// conv1 + bias + LN + ReLU, then h2s & out2 via per-wave MFMA. No barriers.
__global__ __launch_bounds__(256, 4) void k_conv1_fused(
    const uint* __restrict__ hs, const int* __restrict__ ell,
    const int* __restrict__ cnt, const float* __restrict__ dinv,
    const float* __restrict__ b1, const float* __restrict__ lnw_g,
    const float* __restrict__ lnb_g, const _Float16* __restrict__ Bg,
    const float* __restrict__ b3, uint* __restrict__ h2s,
    float* __restrict__ out2, int zoff, int n) {
    __shared__ _Float16 Y[4][16 * 72];   // per-wave A tile, stride 72
    int tid = threadIdx.x;
    int lane = tid & 63, wid = tid >> 6;
    int m = lane & 31, g = lane >> 5;
    int m4 = m * 4;
    {   // zero my wave's tile (rows 4..15 stay zero for the MFMA)
        float4 z = {0.f, 0.f, 0.f, 0.f};
        float4* yb = (float4*)Y[wid];
        for (int i = lane; i < 144; i += 64) yb[i] = z;
    }
    int base = blockIdx.x * 16;
    int nid[4], st[4], P[4];
    int Pmax = 0;
#pragma unroll
    for (int p = 0; p < 4; p++) {
        int node = base + wid * 4 + p;
        if (node >= n) node = n - 1;
        nid[p] = node;
        st[p] = node * ELLW;
        P[p] = cnt[node];                // exact degree (no self)
        Pmax = Pmax > P[p] ? Pmax : P[p];
    }
    Pmax = (Pmax + 7) & ~7;
    auto ldidx = [&](int p, int jb) -> int4 {
        int4 o = *(const int4*)(ell + st[p] + jb + 4 * g);
        int b = jb + 4 * g;
        o.x = (b + 0 < P[p]) ? o.x : zoff;
        o.y = (b + 1 < P[p]) ? o.y : zoff;
        o.z = (b + 2 < P[p]) ? o.z : zoff;
        o.w = (b + 3 < P[p]) ? o.w : zoff;
        return o;
    };
    const char* hsb = (const char*)hs;
    float ax[4], ay[4];
#pragma unroll
    for (int p = 0; p < 4; p++) {        // seed with own (pre-scaled) row
        int sa = (g == 0) ? (nid[p] << 7) : zoff;
        uint us = *(const uint*)(hsb + sa + m4);
        float2 f = __half22float2(*(__half2*)&us);
        ax[p] = f.x; ay[p] = f.y;
    }
    GATHER_BODY(hsb)

    // LN + ReLU in lane-pair layout; write y rows (f16) to the wave's Y tile
    float2 b1v = ((const float2*)b1)[m];
    float2 lw = ((const float2*)lnw_g)[m];
    float2 lb = ((const float2*)lnb_g)[m];
    float dcs[4];
#pragma unroll
    for (int p = 0; p < 4; p++) {
        float axp = ax[p] + __shfl_xor(ax[p], 32, 64);
        float ayp = ay[p] + __shfl_xor(ay[p], 32, 64);
        float dc = dinv[nid[p]];
        dcs[p] = dc;
        float va = fmaf(dc, axp, b1v.x);
        float vb = fmaf(dc, ayp, b1v.y);
        float s = va + vb;
#pragma unroll
        for (int off = 16; off > 0; off >>= 1) s += __shfl_xor(s, off, 64);
        float mu = s * (1.f / 64.f);
        float da = va - mu, db = vb - mu;
        float q = da * da + db * db;
#pragma unroll
        for (int off = 16; off > 0; off >>= 1) q += __shfl_xor(q, off, 64);
        float rstd = rsqrtf(q * (1.f / 64.f) + 1e-5f);
        float yA = fmaxf(fmaf(da * rstd, lw.x, lb.x), 0.f);
        float yB = fmaxf(fmaf(db * rstd, lw.y, lb.y), 0.f);
        if (g == 0) {
            __half2 pk = __floats2half2_rn(yA, yB);
            *(__half2*)&Y[wid][p * 72 + 2 * m] = pk;
        }
    }
    // same-wave LDS producer/consumer: lgkmcnt wait only, no barrier
    int m16 = lane & 15, quad = lane >> 4;
    half8 a0 = *(const half8*)&Y[wid][m16 * 72 + quad * 8];
    half8 a1 = *(const half8*)&Y[wid][m16 * 72 + 32 + quad * 8];
    const half8* Bv = (const half8*)Bg;
    _Float16* h2h = (_Float16*)h2s;
#pragma unroll
    for (int t = 0; t < 4; t++) {        // h2 = y @ W2 (4 col tiles)
        f32x4 acc = {0.f, 0.f, 0.f, 0.f};
        acc = __builtin_amdgcn_mfma_f32_16x16x32_f16(a0, Bv[(t * 2 + 0) * 64 + lane], acc, 0, 0, 0);
        acc = __builtin_amdgcn_mfma_f32_16x16x32_f16(a1, Bv[(t * 2 + 1) * 64 + lane], acc, 0, 0, 0);
#pragma unroll
        for (int r = 0; r < 4; r++) {    // C row quad*4+r: real rows live in quad 0
            int nodep = base + wid * 4 + r;
            if (quad == 0 && nodep < n)
                h2h[(size_t)nodep * 64 + t * 16 + m16] = (_Float16)(acc[r] * dcs[r]);
        }
    }
    {                                    // out2 = sigmoid(y @ W3 + b3)
        f32x4 acc = {0.f, 0.f, 0.f, 0.f};
        acc = __builtin_amdgcn_mfma_f32_16x16x32_f16(a0, Bv[8 * 64 + lane], acc, 0, 0, 0);
        acc = __builtin_amdgcn_mfma_f32_16x16x32_f16(a1, Bv[9 * 64 + lane], acc, 0, 0, 0);
        float bb = b3[m16 < 6 ? m16 : 0];
#pragma unroll
        for (int r = 0; r < 4; r++) {
            int nodep = base + wid * 4 + r;
            if (quad == 0 && m16 < 6 && nodep < n)
                out2[(size_t)nodep * 6 + m16] = 1.f / (1.f + __expf(-(acc[r] + bb)));
        }
    }
}

// conv2: out1 = dc * (self + sum(h2s[slice])) + b2.
__global__ __launch_bounds__(256, 4) void k_conv2(
    const uint* __restrict__ h2s, const int* __restrict__ ell,
    const int* __restrict__ cnt, const float* __restrict__ dinv,
    const float* __restrict__ b2, float* __restrict__ out1, int zoff, int n) {
    int tid = threadIdx.x;
    int lane = tid & 63, wid = tid >> 6;
    int m = lane & 31, g = lane >> 5;
    int m4 = m * 4;
    int base = blockIdx.x * 16;
    int nid[4], st[4], P[4];
    int Pmax = 0;
#pragma unroll
    for (int p = 0; p < 4; p++) {
        int node = base + wid * 4 + p;
        if (node >= n) node = n - 1;
        nid[p] = node;
        st[p] = node * ELLW;
        P[p] = cnt[node];
        Pmax = Pmax > P[p] ? Pmax : P[p];
    }
    Pmax = (Pmax + 7) & ~7;
    auto ldidx = [&](int p, int jb) -> int4 {
        int4 o = *(const int4*)(ell + st[p] + jb + 4 * g);
        int b = jb + 4 * g;
        o.x = (b + 0 < P[p]) ? o.x : zoff;
        o.y = (b + 1 < P[p]) ? o.y : zoff;
        o.z = (b + 2 < P[p]) ? o.z : zoff;
        o.w = (b + 3 < P[p]) ? o.w : zoff;
        return o;
    };
    const char* hsb = (const char*)h2s;
    float ax[4], ay[4];
#pragma unroll
    for (int p = 0; p < 4; p++) {        // seed with own row
        int sa = (g == 0) ? (nid[p] << 7) : zoff;
        uint us = *(const uint*)(hsb + sa + m4);
        float2 f = __half22float2(*(__half2*)&us);
        ax[p] = f.x; ay[p] = f.y;
    }
    GATHER_BODY(hsb)

    float2 b2v = ((const float2*)b2)[m];
#pragma unroll
    for (int p = 0; p < 4; p++) {
        float axp = ax[p] + __shfl_xor(ax[p], 32, 64);
        float ayp = ay[p] + __shfl_xor(ay[p], 32, 64);
        int node = base + wid * 4 + p;
        if (g == 0 && node < n) {
            float dc = dinv[nid[p]];
            float2 r;
            r.x = fmaf(dc, axp, b2v.x);
            r.y = fmaf(dc, ayp, b2v.y);
            ((float2*)out1)[(size_t)node * 32 + m] = r;
        }
    }
}

extern "C" void kernel_launch(void* const* d_in, const int* in_sizes, int n_in,
                              void* d_out, int out_size, void* d_ws, size_t ws_size,
                              hipStream_t stream) {
    const float* x   = (const float*)d_in[0];
    const int*   ei  = (const int*)d_in[1];
    const float* W1  = (const float*)d_in[2];
    const float* b1  = (const float*)d_in[3];
    const float* lnw = (const float*)d_in[4];
    const float* lnb = (const float*)d_in[5];
    const float* W2  = (const float*)d_in[6];
    const float* b2  = (const float*)d_in[7];
    const float* W3  = (const float*)d_in[8];
    const float* b3  = (const float*)d_in[9];

    int n = in_sizes[0] / 128;
    int E = in_sizes[1] / 2;
    const int* row = ei;        // sources
    const int* col = ei + E;    // targets

    char* ws = (char*)d_ws;
    size_t off = 0;
    auto carve = [&](size_t bytes) -> char* {
        char* p = ws + off;
        off = (off + bytes + 255) & ~(size_t)255;
        return p;
    };
    int*   cnt  = (int*)carve(4 * (size_t)n);
    float* dinv = (float*)carve(4 * (size_t)n);
    int*   ell  = (int*)carve(4 * ((size_t)n * ELLW + 256));  // +margin for prefetch
    uint*  hs   = (uint*)carve(128 * ((size_t)n + 1));        // +1 zero row
    uint*  h2s  = (uint*)carve(128 * ((size_t)n + 1));
    _Float16* W1g = (_Float16*)carve(2 * 8192);
    _Float16* Bg  = (_Float16*)carve(2 * 5120);

    float* out1 = (float*)d_out;
    float* out2 = out1 + (size_t)n * 64;
    int zero_off = n << 7;
    int slice_sz = (n + 7) / 8;          // contiguous node slice per XCD

    k_pack<<<52, 256, 0, stream>>>(W1, W2, W3, W1g, Bg);
    k_init<<<(n + 255) / 256, 256, 0, stream>>>(cnt, n);
    // 8 slices x 256 edge-chunks; blockIdx&7 = slice -> XCD round-robin
    k_scatter<<<8 * 256, 256, 0, stream>>>(row, col, cnt, ell, E, slice_sz);
    k_dinv<<<(n + 255) / 256, 256, 0, stream>>>(cnt, dinv, n);
    k_gemm1<<<(n + 63) / 64, 256, 0, stream>>>(x, W1g, dinv, hs, h2s, n);
    k_conv1_fused<<<(n + 15) / 16, 256, 0, stream>>>(hs, ell, cnt, dinv,
                                                     b1, lnw, lnb, Bg, b3,
                                                     h2s, out2, zero_off, n);
    k_conv2<<<(n + 15) / 16, 256, 0, stream>>>(h2s, ell, cnt, dinv, b2,
                                               out1, zero_off, n);
}

// Round 2
// 187.579 us; speedup vs baseline: 1.1204x; 1.0793x over previous
//
#include <hip/hip_runtime.h>
#include <hip/hip_fp16.h>
#include <math.h>

// ---------------------------------------------------------------------------
// GCN encoder. Aggregation = gather over a single-pass device-built ELL table:
//   k_scatter: r = atomicAdd(&cnt[c],1); ell[c*48+r] = src_row_byte_offset
// v2: XCD-sliced scatter (slice = blockIdx&7 -> per-XCD L2-resident ell slice).
// v3: 8-byte gather loads (16 lanes x uint2 per edge row, 4 edge groups/wave)
//     -> half the VMEM instructions in the latency-bound gather loop;
//     dinv recomputed from cnt everywhere (k_dinv kernel + buffer deleted);
//     k_init folded into k_pack (5 launches total).
// Rows are pre-scaled fp16: hs[r] = dinv[r]*(x@W1)[r], h2s[r] = dinv[r]*h2[r];
// self loop is handled by initializing the accumulator from the node's own row.
// Gather entries beyond exact degree are clamped (cndmask) to a zero row.
// ---------------------------------------------------------------------------

#define ELLW 48

typedef _Float16 half8 __attribute__((ext_vector_type(8)));
typedef float f32x4 __attribute__((ext_vector_type(4)));

// Pack W1 into f16 B-frag layout (4 col-tiles x 4 k-steps) and [W2|W3] into
// 5 tiles x 2 k-steps; blocks >= 52 zero the cnt array.
__global__ void k_setup(const float* __restrict__ W1, const float* __restrict__ W2,
                        const float* __restrict__ W3, _Float16* __restrict__ W1g,
                        _Float16* __restrict__ Bg, int* __restrict__ cnt, int n) {
    if (blockIdx.x >= 52) {
        int i = (blockIdx.x - 52) * 256 + threadIdx.x;
        if (i < n) cnt[i] = 0;
        return;
    }
    int idx = blockIdx.x * 256 + threadIdx.x;
    if (idx < 8192) {
        int j = idx & 7, L = (idx >> 3) & 63, s = (idx >> 9) & 3, t = idx >> 11;
        int k = s * 32 + (L >> 4) * 8 + j;
        int c = t * 16 + (L & 15);
        W1g[idx] = (_Float16)W1[k * 64 + c];
    } else if (idx < 8192 + 5120) {
        int i2 = idx - 8192;
        int j = i2 & 7, L = (i2 >> 3) & 63, s = (i2 >> 9) & 1, u = i2 >> 10;
        int k = s * 32 + (L >> 4) * 8 + j;
        int c = (L & 15);
        float v;
        if (u < 4) v = W2[k * 64 + u * 16 + c];
        else v = (c < 6) ? W3[k * 6 + c] : 0.f;
        Bg[i2] = (_Float16)v;
    }
}

// XCD-sliced single-pass ELL build: rank comes from the atomic itself.
// slice = blockIdx&7 -> round-robin XCD mapping; each slice's cnt+ell working
// set (~25KB + ~1.2MB) stays resident in that XCD's L2 so writebacks merge.
__global__ __launch_bounds__(256) void k_scatter(
    const int* __restrict__ row, const int* __restrict__ col,
    int* __restrict__ cnt, int* __restrict__ ell, int E, int slice_sz) {
    int slice = blockIdx.x & 7;
    int lo = slice * slice_sz;
    int hi = lo + slice_sz;
    int nchunk = gridDim.x >> 3;
    int stride = nchunk * 256;
    int v0 = (blockIdx.x >> 3) * 256 + threadIdx.x;
    int nv = E >> 2;
    const int4* c4p = (const int4*)col;
    const int4* r4p = (const int4*)row;
    for (int v = v0; v < nv; v += stride) {
        int4 c4 = c4p[v];
        int4 r4 = r4p[v];
        if (c4.x >= lo && c4.x < hi) {
            int rk = atomicAdd(&cnt[c4.x], 1);
            if (rk < ELLW) ell[c4.x * ELLW + rk] = r4.x << 7;
        }
        if (c4.y >= lo && c4.y < hi) {
            int rk = atomicAdd(&cnt[c4.y], 1);
            if (rk < ELLW) ell[c4.y * ELLW + rk] = r4.y << 7;
        }
        if (c4.z >= lo && c4.z < hi) {
            int rk = atomicAdd(&cnt[c4.z], 1);
            if (rk < ELLW) ell[c4.z * ELLW + rk] = r4.z << 7;
        }
        if (c4.w >= lo && c4.w < hi) {
            int rk = atomicAdd(&cnt[c4.w], 1);
            if (rk < ELLW) ell[c4.w * ELLW + rk] = r4.w << 7;
        }
    }
    if ((blockIdx.x >> 3) == 0) {        // tail edges (E % 4)
        for (int e = (nv << 2) + threadIdx.x; e < E; e += 256) {
            int c = col[e];
            if (c >= lo && c < hi) {
                int rk = atomicAdd(&cnt[c], 1);
                if (rk < ELLW) ell[c * ELLW + rk] = row[e] << 7;
            }
        }
    }
}

// hs = (x @ W1) * dinv, via f16 MFMA. Block = 4 waves x 16 nodes = 64 nodes.
__global__ __launch_bounds__(256, 4) void k_gemm1(
    const float* __restrict__ x, const _Float16* __restrict__ W1g,
    const int* __restrict__ cnt, uint* __restrict__ hs,
    uint* __restrict__ h2s, int n) {
    int tid = threadIdx.x;
    if (blockIdx.x == 0) {               // zero rows for clamped gathers
        if (tid < 32) hs[(size_t)n * 32 + tid] = 0u;
        else if (tid < 64) h2s[(size_t)n * 32 + (tid - 32)] = 0u;
    }
    int lane = tid & 63, wid = tid >> 6;
    int m16 = lane & 15, quad = lane >> 4;
    int node0 = blockIdx.x * 64 + wid * 16;
    int arow = node0 + m16;
    if (arow >= n) arow = n - 1;
    const float* xr = x + (size_t)arow * 128;
    half8 A[4];
#pragma unroll
    for (int s = 0; s < 4; s++) {
        const float4* p = (const float4*)(xr + s * 32 + quad * 8);
        float4 f0 = p[0], f1 = p[1];
        half8 a;
        a[0] = (_Float16)f0.x; a[1] = (_Float16)f0.y;
        a[2] = (_Float16)f0.z; a[3] = (_Float16)f0.w;
        a[4] = (_Float16)f1.x; a[5] = (_Float16)f1.y;
        a[6] = (_Float16)f1.z; a[7] = (_Float16)f1.w;
        A[s] = a;
    }
    float dsc[4];
#pragma unroll
    for (int r = 0; r < 4; r++) {
        int nd = node0 + quad * 4 + r;
        dsc[r] = rsqrtf((float)(cnt[nd < n ? nd : n - 1] + 1));
    }
    const half8* Wv = (const half8*)W1g;
#pragma unroll
    for (int t = 0; t < 4; t++) {
        f32x4 acc = {0.f, 0.f, 0.f, 0.f};
#pragma unroll
        for (int s = 0; s < 4; s++)
            acc = __builtin_amdgcn_mfma_f32_16x16x32_f16(A[s], Wv[(t * 4 + s) * 64 + lane], acc, 0, 0, 0);
#pragma unroll
        for (int r = 0; r < 4; r++) {
            int nd = node0 + quad * 4 + r;
            float v = acc[r] * dsc[r];
            float vo = __shfl_xor(v, 1, 64);
            if (!(m16 & 1) && nd < n) {
                __half2 pk = __floats2half2_rn(v, vo);
                hs[(size_t)nd * 32 + t * 8 + (m16 >> 1)] = *(uint*)&pk;
            }
        }
    }
}

// Branchless pipelined 4-node gather, 8B loads: 16 lanes x uint2 cover one
// 128B row; g = lane>>4 selects one of 4 edge pairs per step. acc[p] holds
// components 4*m16 .. 4*m16+3. Accumulators pre-seeded with self rows.
#define GATHER_BODY8(SRC)                                                     \
    int2 o1[4], o2[4];                                                        \
    uint4 u0[4], u1[4];                                                       \
    {                                                                         \
        int2 o0[4];                                                           \
        _Pragma("unroll") for (int p = 0; p < 4; p++) o0[p] = ldidx2(p, 0);   \
        _Pragma("unroll") for (int p = 0; p < 4; p++) o1[p] = ldidx2(p, 8);   \
        _Pragma("unroll") for (int p = 0; p < 4; p++) {                       \
            uint2 t0 = *(const uint2*)(SRC + o0[p].x + m8);                   \
            uint2 t1 = *(const uint2*)(SRC + o0[p].y + m8);                   \
            u0[p].x = t0.x; u0[p].y = t0.y; u0[p].z = t1.x; u0[p].w = t1.y;   \
        }                                                                     \
    }                                                                         \
    for (int jb = 0; jb < Pmax; jb += 8) {                                    \
        _Pragma("unroll") for (int p = 0; p < 4; p++) o2[p] = ldidx2(p, jb + 16); \
        _Pragma("unroll") for (int p = 0; p < 4; p++) {                       \
            uint2 t0 = *(const uint2*)(SRC + o1[p].x + m8);                   \
            uint2 t1 = *(const uint2*)(SRC + o1[p].y + m8);                   \
            u1[p].x = t0.x; u1[p].y = t0.y; u1[p].z = t1.x; u1[p].w = t1.y;   \
        }                                                                     \
        _Pragma("unroll") for (int p = 0; p < 4; p++) {                       \
            float2 f;                                                         \
            f = __half22float2(*(__half2*)&u0[p].x); acc[p][0] += f.x; acc[p][1] += f.y; \
            f = __half22float2(*(__half2*)&u0[p].y); acc[p][2] += f.x; acc[p][3] += f.y; \
            f = __half22float2(*(__half2*)&u0[p].z); acc[p][0] += f.x; acc[p][1] += f.y; \
            f = __half22float2(*(__half2*)&u0[p].w); acc[p][2] += f.x; acc[p][3] += f.y; \
        }                                                                     \
        _Pragma("unroll") for (int p = 0; p < 4; p++) { o1[p] = o2[p]; u0[p] = u1[p]; } \
    }

#define GATHER_PROLOG(SRC_T)                                                  \
    int nid[4], st[4], P[4];                                                  \
    int Pmax = 0;                                                             \
    _Pragma("unroll") for (int p = 0; p < 4; p++) {                           \
        int node = base + wid * 4 + p;                                        \
        if (node >= n) node = n - 1;                                          \
        nid[p] = node;                                                        \
        st[p] = node * ELLW;                                                  \
        P[p] = cnt[node];                                                     \
        Pmax = Pmax > P[p] ? Pmax : P[p];                                     \
    }                                                                         \
    Pmax = (Pmax + 7) & ~7;                                                   \
    auto ldidx2 = [&](int p, int jb) -> int2 {                                \
        int2 o = *(const int2*)(ell + st[p] + jb + 2 * g);                    \
        int b = jb + 2 * g;                                                   \
        o.x = (b + 0 < P[p]) ? o.x : zoff;                                    \
        o.y = (b + 1 < P[p]) ? o.y : zoff;                                    \
        return o;                                                             \
    };                                                                        \
    const char* hsb = (const char*)(SRC_T);                                   \
    f32x4 acc[4];                                                             \
    _Pragma("unroll") for (int p = 0; p < 4; p++) {                           \
        int sa = (g == 0) ? (nid[p] << 7) : zoff;                             \
        uint2 us = *(const uint2*)(hsb + sa + m8);                            \
        float2 f0 = __half22float2(*(__half2*)&us.x);                         \
        float2 f1 = __half22float2(*(__half2*)&us.y);                         \
        acc[p][0] = f0.x; acc[p][1] = f0.y; acc[p][2] = f1.x; acc[p][3] = f1.y; \
    }

// conv1 + bias + LN + ReLU, then h2s & out2 via per-wave MFMA. No barriers.
__global__ __launch_bounds__(256, 4) void k_conv1_fused(
    const uint* __restrict__ hs, const int* __restrict__ ell,
    const int* __restrict__ cnt, const float* __restrict__ b1,
    const float* __restrict__ lnw_g, const float* __restrict__ lnb_g,
    const _Float16* __restrict__ Bg, const float* __restrict__ b3,
    uint* __restrict__ h2s, float* __restrict__ out2, int zoff, int n) {
    __shared__ _Float16 Y[4][16 * 72];   // per-wave A tile, stride 72
    int tid = threadIdx.x;
    int lane = tid & 63, wid = tid >> 6;
    int m16l = lane & 15, g = lane >> 4;
    int m8 = m16l * 8;
    {   // zero my wave's tile (rows 4..15 stay zero for the MFMA)
        float4 z = {0.f, 0.f, 0.f, 0.f};
        float4* yb = (float4*)Y[wid];
        for (int i = lane; i < 144; i += 64) yb[i] = z;
    }
    int base = blockIdx.x * 16;
    GATHER_PROLOG(hs)
    GATHER_BODY8(hsb)

    // LN + ReLU: lane m16 owns comps 4*m16..4*m16+3; write y rows to Y tile
    float4 b1v = ((const float4*)b1)[m16l];
    float4 lw = ((const float4*)lnw_g)[m16l];
    float4 lb = ((const float4*)lnb_g)[m16l];
    float dcs[4];
#pragma unroll
    for (int p = 0; p < 4; p++) {
        float s0 = acc[p][0], s1 = acc[p][1], s2 = acc[p][2], s3 = acc[p][3];
        s0 += __shfl_xor(s0, 16, 64); s0 += __shfl_xor(s0, 32, 64);
        s1 += __shfl_xor(s1, 16, 64); s1 += __shfl_xor(s1, 32, 64);
        s2 += __shfl_xor(s2, 16, 64); s2 += __shfl_xor(s2, 32, 64);
        s3 += __shfl_xor(s3, 16, 64); s3 += __shfl_xor(s3, 32, 64);
        float dc = rsqrtf((float)(P[p] + 1));
        dcs[p] = dc;
        float v0 = fmaf(dc, s0, b1v.x);
        float v1 = fmaf(dc, s1, b1v.y);
        float v2 = fmaf(dc, s2, b1v.z);
        float v3 = fmaf(dc, s3, b1v.w);
        float s = v0 + v1 + v2 + v3;
#pragma unroll
        for (int off = 8; off > 0; off >>= 1) s += __shfl_xor(s, off, 64);
        float mu = s * (1.f / 64.f);
        float d0 = v0 - mu, d1 = v1 - mu, d2 = v2 - mu, d3 = v3 - mu;
        float q = d0 * d0 + d1 * d1 + d2 * d2 + d3 * d3;
#pragma unroll
        for (int off = 8; off > 0; off >>= 1) q += __shfl_xor(q, off, 64);
        float rstd = rsqrtf(q * (1.f / 64.f) + 1e-5f);
        float y0 = fmaxf(fmaf(d0 * rstd, lw.x, lb.x), 0.f);
        float y1 = fmaxf(fmaf(d1 * rstd, lw.y, lb.y), 0.f);
        float y2 = fmaxf(fmaf(d2 * rstd, lw.z, lb.z), 0.f);
        float y3 = fmaxf(fmaf(d3 * rstd, lw.w, lb.w), 0.f);
        if (g == 0) {
            __half2 pk0 = __floats2half2_rn(y0, y1);
            __half2 pk1 = __floats2half2_rn(y2, y3);
            uint2 pk;
            pk.x = *(uint*)&pk0; pk.y = *(uint*)&pk1;
            *(uint2*)&Y[wid][p * 72 + 4 * m16l] = pk;
        }
    }
    // same-wave LDS producer/consumer: lgkmcnt wait only, no barrier
    int m16 = lane & 15, quad = lane >> 4;
    half8 a0 = *(const half8*)&Y[wid][m16 * 72 + quad * 8];
    half8 a1 = *(const half8*)&Y[wid][m16 * 72 + 32 + quad * 8];
    const half8* Bv = (const half8*)Bg;
    _Float16* h2h = (_Float16*)h2s;
#pragma unroll
    for (int t = 0; t < 4; t++) {        // h2 = y @ W2 (4 col tiles)
        f32x4 acc2 = {0.f, 0.f, 0.f, 0.f};
        acc2 = __builtin_amdgcn_mfma_f32_16x16x32_f16(a0, Bv[(t * 2 + 0) * 64 + lane], acc2, 0, 0, 0);
        acc2 = __builtin_amdgcn_mfma_f32_16x16x32_f16(a1, Bv[(t * 2 + 1) * 64 + lane], acc2, 0, 0, 0);
#pragma unroll
        for (int r = 0; r < 4; r++) {    // C row quad*4+r: real rows live in quad 0
            int nodep = base + wid * 4 + r;
            if (quad == 0 && nodep < n)
                h2h[(size_t)nodep * 64 + t * 16 + m16] = (_Float16)(acc2[r] * dcs[r]);
        }
    }
    {                                    // out2 = sigmoid(y @ W3 + b3)
        f32x4 acc2 = {0.f, 0.f, 0.f, 0.f};
        acc2 = __builtin_amdgcn_mfma_f32_16x16x32_f16(a0, Bv[8 * 64 + lane], acc2, 0, 0, 0);
        acc2 = __builtin_amdgcn_mfma_f32_16x16x32_f16(a1, Bv[9 * 64 + lane], acc2, 0, 0, 0);
        float bb = b3[m16 < 6 ? m16 : 0];
#pragma unroll
        for (int r = 0; r < 4; r++) {
            int nodep = base + wid * 4 + r;
            if (quad == 0 && m16 < 6 && nodep < n)
                out2[(size_t)nodep * 6 + m16] = 1.f / (1.f + __expf(-(acc2[r] + bb)));
        }
    }
}

// conv2: out1 = dc * (self + sum(h2s[slice])) + b2.
__global__ __launch_bounds__(256, 4) void k_conv2(
    const uint* __restrict__ h2s, const int* __restrict__ ell,
    const int* __restrict__ cnt, const float* __restrict__ b2,
    float* __restrict__ out1, int zoff, int n) {
    int tid = threadIdx.x;
    int lane = tid & 63, wid = tid >> 6;
    int m16l = lane & 15, g = lane >> 4;
    int m8 = m16l * 8;
    int base = blockIdx.x * 16;
    GATHER_PROLOG(h2s)
    GATHER_BODY8(hsb)

    float4 b2v = ((const float4*)b2)[m16l];
#pragma unroll
    for (int p = 0; p < 4; p++) {
        float s0 = acc[p][0], s1 = acc[p][1], s2 = acc[p][2], s3 = acc[p][3];
        s0 += __shfl_xor(s0, 16, 64); s0 += __shfl_xor(s0, 32, 64);
        s1 += __shfl_xor(s1, 16, 64); s1 += __shfl_xor(s1, 32, 64);
        s2 += __shfl_xor(s2, 16, 64); s2 += __shfl_xor(s2, 32, 64);
        s3 += __shfl_xor(s3, 16, 64); s3 += __shfl_xor(s3, 32, 64);
        int node = base + wid * 4 + p;
        if (g == 0 && node < n) {
            float dc = rsqrtf((float)(P[p] + 1));
            float4 r;
            r.x = fmaf(dc, s0, b2v.x);
            r.y = fmaf(dc, s1, b2v.y);
            r.z = fmaf(dc, s2, b2v.z);
            r.w = fmaf(dc, s3, b2v.w);
            ((float4*)out1)[(size_t)node * 16 + m16l] = r;
        }
    }
}

extern "C" void kernel_launch(void* const* d_in, const int* in_sizes, int n_in,
                              void* d_out, int out_size, void* d_ws, size_t ws_size,
                              hipStream_t stream) {
    const float* x   = (const float*)d_in[0];
    const int*   ei  = (const int*)d_in[1];
    const float* W1  = (const float*)d_in[2];
    const float* b1  = (const float*)d_in[3];
    const float* lnw = (const float*)d_in[4];
    const float* lnb = (const float*)d_in[5];
    const float* W2  = (const float*)d_in[6];
    const float* b2  = (const float*)d_in[7];
    const float* W3  = (const float*)d_in[8];
    const float* b3  = (const float*)d_in[9];

    int n = in_sizes[0] / 128;
    int E = in_sizes[1] / 2;
    const int* row = ei;        // sources
    const int* col = ei + E;    // targets

    char* ws = (char*)d_ws;
    size_t off = 0;
    auto carve = [&](size_t bytes) -> char* {
        char* p = ws + off;
        off = (off + bytes + 255) & ~(size_t)255;
        return p;
    };
    int*   cnt  = (int*)carve(4 * (size_t)n);
    int*   ell  = (int*)carve(4 * ((size_t)n * ELLW + 256));  // +margin for prefetch
    uint*  hs   = (uint*)carve(128 * ((size_t)n + 1));        // +1 zero row
    uint*  h2s  = (uint*)carve(128 * ((size_t)n + 1));
    _Float16* W1g = (_Float16*)carve(2 * 8192);
    _Float16* Bg  = (_Float16*)carve(2 * 5120);

    float* out1 = (float*)d_out;
    float* out2 = out1 + (size_t)n * 64;
    int zero_off = n << 7;
    int slice_sz = (n + 7) / 8;          // contiguous node slice per XCD

    k_setup<<<52 + (n + 255) / 256, 256, 0, stream>>>(W1, W2, W3, W1g, Bg, cnt, n);
    // 8 slices x 256 edge-chunks; blockIdx&7 = slice -> XCD round-robin
    k_scatter<<<8 * 256, 256, 0, stream>>>(row, col, cnt, ell, E, slice_sz);
    k_gemm1<<<(n + 63) / 64, 256, 0, stream>>>(x, W1g, cnt, hs, h2s, n);
    k_conv1_fused<<<(n + 15) / 16, 256, 0, stream>>>(hs, ell, cnt,
                                                     b1, lnw, lnb, Bg, b3,
                                                     h2s, out2, zero_off, n);
    k_conv2<<<(n + 15) / 16, 256, 0, stream>>>(h2s, ell, cnt, b2,
                                               out1, zero_off, n);
}